// Round 10
// baseline (404.751 us; speedup 1.0000x reference)
//
#include <hip/hip_runtime.h>

// MessagePassingNet on MI355X — Round 9b (compile fix of R9):
//   * edge kernel v7: 32 edges/wave — each B-fragment load feeds 2 A-tiles
//     (6 MFMAs) => weight L1/L2 traffic halved (R8 lesson: occupancy above
//     ~40% is free; per-wave efficiency is the binding constraint).
//   * non-temporal loads on random Ys gather via native ext_vector float4
//     (__builtin_nontemporal_load rejects HIP_vector_type).
//   * rest of pipeline as R8 (7 dispatches, ds_sorted, wave-autonomous).

constexpr int N_ATOMS = 131072;
constexpr int N_EDGES = 1048576;
constexpr int DD      = 64;
constexpr int OUTD    = 16;
constexpr int SH      = 72;   // halfword row stride for hi/lo LDS tiles

typedef __bf16 bf16x8 __attribute__((ext_vector_type(8)));
typedef float  f32x4  __attribute__((ext_vector_type(4)));
typedef unsigned short u16x8 __attribute__((ext_vector_type(8)));

#define DEV_INLINE __device__ __forceinline__

DEV_INLINE float relu(float x) { return x > 0.f ? x : 0.f; }

DEV_INLINE unsigned short bfbits(float x) {
  __bf16 h = (__bf16)x;
  return __builtin_bit_cast(unsigned short, h);
}
DEV_INLINE float bfval(unsigned short u) {
  unsigned int v = ((unsigned int)u) << 16;
  return __builtin_bit_cast(float, v);
}
DEV_INLINE f32x4 mfma16(bf16x8 a, bf16x8 b, f32x4 c) {
  return __builtin_amdgcn_mfma_f32_16x16x32_bf16(a, b, c, 0, 0, 0);
}
DEV_INLINE bf16x8 ldfrag(const unsigned short* p) { return *(const bf16x8*)p; }

// non-temporal 16B load: builtin requires a native vector type, not
// HIP_vector_type<float,4>. Load as ext_vector f32x4 and repackage.
DEV_INLINE float4 ldnt(const float4* p) {
  f32x4 v = __builtin_nontemporal_load((const f32x4*)p);
  return make_float4(v.x, v.y, v.z, v.w);
}

// split 8 floats (two float4) into bf16 hi/lo A-fragments
DEV_INLINE void mk_frag(float4 a0, float4 a1, bf16x8& fh, bf16x8& fl) {
  const float v[8] = {a0.x, a0.y, a0.z, a0.w, a1.x, a1.y, a1.z, a1.w};
  u16x8 hh, ll;
#pragma unroll
  for (int i = 0; i < 8; ++i) {
    unsigned short h = bfbits(v[i]);
    hh[i] = h;
    ll[i] = bfbits(v[i] - bfval(h));
  }
  fh = __builtin_bit_cast(bf16x8, hh);
  fl = __builtin_bit_cast(bf16x8, ll);
}

// ===========================================================================
// fused_k1: [0,4096) histogram | [4096,6144) zero new_states | [6144,6156)
// weight pack. Sections: 0=W0d 1=W0s 2=W1 3=W2 4=FC1 5=FC2.
// fo(sec,j,s,l) = sec*4096 + ((j*2+s)*64 + l)*8
// ===========================================================================
__global__ __launch_bounds__(256, 4)
void fused_k1(const int* __restrict__ edge_dst,
              const float* __restrict__ w0, const float* __restrict__ w1,
              const float* __restrict__ w2, const float* __restrict__ f1,
              const float* __restrict__ f2,
              int* __restrict__ counters,
              float* __restrict__ new_states,
              unsigned short* __restrict__ whi, unsigned short* __restrict__ wlo)
{
  const int t = threadIdx.x, b = blockIdx.x;

  if (b < 4096) {
    int i = b * 256 + t;
    atomicAdd(&counters[edge_dst[i]], 1);
  } else if (b < 6144) {
    float4* ns4 = (float4*)new_states;
    const int n4 = N_ATOMS * DD / 4;
    for (int i = (b - 4096) * 256 + t; i < n4; i += 2048 * 256)
      ns4[i] = make_float4(0.f, 0.f, 0.f, 0.f);
  } else {
    int tid = (b - 6144) * 256 + t;
    int sec = tid >> 9, rel = tid & 511;
    const float* w; int rowoff = 0;
    switch (sec) {
      case 0: w = w0; rowoff = 0;  break;
      case 1: w = w0; rowoff = 64; break;
      case 2: w = w1; break;
      case 3: w = w2; break;
      case 4: w = f1; break;
      default: w = f2; break;
    }
    const int tile = rel >> 6, lane = rel & 63;
    const int j = tile >> 1, s = tile & 1;
    const int n  = j * 16 + (lane & 15);
    const int kb = s * 32 + (lane >> 4) * 8;
    const int out = sec * 4096 + (tile * 64 + lane) * 8;
#pragma unroll
    for (int i = 0; i < 8; ++i) {
      float v = w[(rowoff + kb + i) * 64 + n];
      unsigned short h = bfbits(v);
      whi[out + i] = h;
      wlo[out + i] = bfbits(v - bfval(h));
    }
  }
}

// ===========================================================================
__global__ void blocksum_kernel(const int* __restrict__ counters,
                                int* __restrict__ partial) {
  __shared__ int s[256];
  int t = threadIdx.x;
  s[t] = counters[blockIdx.x * 256 + t];
  __syncthreads();
  for (int off = 128; off > 0; off >>= 1) {
    if (t < off) s[t] += s[t + off];
    __syncthreads();
  }
  if (t == 0) partial[blockIdx.x] = s[0];
}

__global__ void scanwrite_kernel(const int* __restrict__ counters,
                                 const int* __restrict__ partial,
                                 int* __restrict__ cursor) {
  __shared__ int s[256];
  __shared__ int pS[256];
  int t = threadIdx.x, b = blockIdx.x;

  int acc = 0;
  int p0 = partial[t];       if (t < b)       acc += p0;
  int p1 = partial[256 + t]; if (256 + t < b) acc += p1;
  pS[t] = acc;
  __syncthreads();
  for (int off = 128; off > 0; off >>= 1) {
    if (t < off) pS[t] += pS[t + off];
    __syncthreads();
  }
  const int base = pS[0];

  int v = counters[b * 256 + t];
  s[t] = v;
  __syncthreads();
  for (int off = 1; off < 256; off <<= 1) {
    int x = (t >= off) ? s[t - off] : 0;
    __syncthreads();
    s[t] += x;
    __syncthreads();
  }
  cursor[b * 256 + t] = base + s[t] - v;  // exclusive
}

// ===========================================================================
// fused_k2: [0,4096) scatter -> ds_sorted/eids | [4096,6144) atom_pre
// (register A-fragments, zero LDS, zero barriers).
// ===========================================================================
__global__ __launch_bounds__(256, 4)
void fused_k2(const float* __restrict__ atom_states,
              const int* __restrict__ edge_src,
              const int* __restrict__ edge_dst,
              int* __restrict__ cursor,
              int2* __restrict__ ds_sorted,
              int* __restrict__ eids,
              int use_ds,
              const unsigned short* __restrict__ whi,
              const unsigned short* __restrict__ wlo,
              const float* __restrict__ b0,
              float* __restrict__ Yd, float* __restrict__ Ys)
{
  const int t = threadIdx.x, b = blockIdx.x;

  if (b < 4096) {                       // scatter
    int i = b * 256 + t;
    int d = edge_dst[i];
    int pos = atomicAdd(&cursor[d], 1);
    if (use_ds) ds_sorted[pos] = make_int2(d, edge_src[i]);
    else        eids[pos] = i;
    return;
  }

  const int a0 = (b - 4096) * 64;
  const int l  = t & 63;
  const int w  = t >> 6;
  const int fi = (l >> 4) * 2;
  const int cc = l & 15;
  const int arow = a0 + w * 16 + (l & 15);

  bf16x8 xh[2], xl[2];
  {
    const float4* px = (const float4*)(atom_states + (size_t)arow * DD);
#pragma unroll
    for (int s = 0; s < 2; ++s) {
      float4 x0 = px[s * 8 + fi], x1 = px[s * 8 + fi + 1];
      mk_frag(x0, x1, xh[s], xl[s]);
    }
  }

#pragma unroll
  for (int side = 0; side < 2; ++side) {
    f32x4 acc[4];
#pragma unroll
    for (int j = 0; j < 4; ++j) acc[j] = (f32x4){0.f, 0.f, 0.f, 0.f};
#pragma unroll
    for (int s = 0; s < 2; ++s) {
#pragma unroll
      for (int j = 0; j < 4; ++j) {
        const int fo = side * 4096 + ((j * 2 + s) * 64 + l) * 8;
        bf16x8 bh = ldfrag(whi + fo);
        bf16x8 bl = ldfrag(wlo + fo);
        acc[j] = mfma16(xl[s], bh, acc[j]);
        acc[j] = mfma16(xh[s], bl, acc[j]);
        acc[j] = mfma16(xh[s], bh, acc[j]);
      }
    }
    float* Y = side ? Ys : Yd;
#pragma unroll
    for (int j = 0; j < 4; ++j) {
      const int   c  = j * 16 + cc;
      const float bb = side ? 0.f : b0[c];
#pragma unroll
      for (int i = 0; i < 4; ++i) {
        const int r = w * 16 + (l >> 4) * 4 + i;
        Y[(size_t)(a0 + r) * DD + c] = acc[j][i] + bb;
      }
    }
  }
}

// ===========================================================================
// edge_kernel_v7: wave-autonomous, barrier-free, 32 edges/wave (2 A-tiles per
// B-fragment load). h1 gathered straight into register A-fragments; Ys loads
// non-temporal. LDS = per-wave 32-row h2 slice (msg aliases). 36.9 KB/WG.
// ===========================================================================
__global__ __launch_bounds__(256, 4)
void edge_kernel_v7(const float* __restrict__ Yd,
                    const float* __restrict__ Ys,
                    const int2* __restrict__ ds_sorted,
                    const int* __restrict__ eids,
                    const int* __restrict__ edge_src,
                    const int* __restrict__ edge_dst,
                    int use_ds,
                    const unsigned short* __restrict__ whi,
                    const unsigned short* __restrict__ wlo,
                    const float* __restrict__ b1,
                    const float* __restrict__ b2,
                    float* __restrict__ new_states)
{
  __shared__ __align__(16) unsigned short H2[4][2 * 32 * SH];  // h2 hi|lo; msg aliases

  const int t = threadIdx.x;
  const int w = t >> 6;
  const int l = t & 63;
  const int e0 = blockIdx.x * 128 + w * 32;

  unsigned short* h2 = H2[w];            // hi rows 0..31 at 0, lo at 32*SH
  float* msg = (float*)H2[w];            // 32*SH floats = slice, exact

  // ---- indices: lanes 0..31 hold the wave's 32 edges
  int d = 0, s = 0;
  if (l < 32) {
    if (use_ds) {
      int2 ds = ds_sorted[e0 + l];
      d = ds.x; s = ds.y;
    } else {
      int eid = eids[e0 + l];
      d = edge_dst[eid];
      s = edge_src[eid];
    }
  }

  const int m  = l & 15;                 // edge within each 16-tile
  const int fi = (l >> 4) * 2;           // float4 index within 32-float k-step
  const int cc = l & 15;

  // ---- gather h1 = relu(Yd[dst]+Ys[src]) into A-fragments for 2 tiles
  bf16x8 a1h[2][2], a1l[2][2];           // [tile][s2]
#pragma unroll
  for (int tile = 0; tile < 2; ++tile) {
    const int dm = __shfl(d, tile * 16 + m);
    const int sm = __shfl(s, tile * 16 + m);
    const float4* pd = (const float4*)(Yd + (size_t)dm * DD);
    const float4* ps = (const float4*)(Ys + (size_t)sm * DD);
#pragma unroll
    for (int s2 = 0; s2 < 2; ++s2) {
      float4 x0 = pd[s2 * 8 + fi], x1 = pd[s2 * 8 + fi + 1];
      float4 y0 = ldnt(ps + s2 * 8 + fi), y1 = ldnt(ps + s2 * 8 + fi + 1);
      float4 r0 = make_float4(relu(x0.x + y0.x), relu(x0.y + y0.y),
                              relu(x0.z + y0.z), relu(x0.w + y0.w));
      float4 r1 = make_float4(relu(x1.x + y1.x), relu(x1.y + y1.y),
                              relu(x1.z + y1.z), relu(x1.w + y1.w));
      mk_frag(r0, r1, a1h[tile][s2], a1l[tile][s2]);
    }
  }

  f32x4 acc[2][4];

  // ---- layer 1 (A = regs, B sec 2): each B-fragment feeds both tiles
#pragma unroll
  for (int tile = 0; tile < 2; ++tile)
#pragma unroll
    for (int j = 0; j < 4; ++j) acc[tile][j] = (f32x4){0.f, 0.f, 0.f, 0.f};
#pragma unroll
  for (int s2 = 0; s2 < 2; ++s2) {
#pragma unroll
    for (int j = 0; j < 4; ++j) {
      const int fo = 2 * 4096 + ((j * 2 + s2) * 64 + l) * 8;
      bf16x8 bh = ldfrag(whi + fo);
      bf16x8 bl = ldfrag(wlo + fo);
#pragma unroll
      for (int tile = 0; tile < 2; ++tile) {
        acc[tile][j] = mfma16(a1l[tile][s2], bh, acc[tile][j]);
        acc[tile][j] = mfma16(a1h[tile][s2], bl, acc[tile][j]);
        acc[tile][j] = mfma16(a1h[tile][s2], bh, acc[tile][j]);
      }
    }
  }
#pragma unroll
  for (int tile = 0; tile < 2; ++tile) {
#pragma unroll
    for (int j = 0; j < 4; ++j) {
      const int   c  = j * 16 + cc;
      const float bb = b1[c];
#pragma unroll
      for (int i = 0; i < 4; ++i) {
        const int r = tile * 16 + (l >> 4) * 4 + i;   // C layout rows
        float v = relu(acc[tile][j][i] + bb);
        unsigned short hi = bfbits(v);
        h2[r * SH + c] = hi;
        h2[32 * SH + r * SH + c] = bfbits(v - bfval(hi));
      }
    }
  }

  // ---- layer 2 (A = h2 from LDS, B sec 3) -> msg fp32 (aliases h2;
  // same-wave in-order LDS: reads complete before epilogue writes)
#pragma unroll
  for (int tile = 0; tile < 2; ++tile)
#pragma unroll
    for (int j = 0; j < 4; ++j) acc[tile][j] = (f32x4){0.f, 0.f, 0.f, 0.f};
  const int kq = (l >> 4) * 8;
#pragma unroll
  for (int s2 = 0; s2 < 2; ++s2) {
    bf16x8 ah[2], al[2];
#pragma unroll
    for (int tile = 0; tile < 2; ++tile) {
      const int mrow = tile * 16 + m;
      ah[tile] = ldfrag(&h2[mrow * SH + s2 * 32 + kq]);
      al[tile] = ldfrag(&h2[32 * SH + mrow * SH + s2 * 32 + kq]);
    }
#pragma unroll
    for (int j = 0; j < 4; ++j) {
      const int fo = 3 * 4096 + ((j * 2 + s2) * 64 + l) * 8;
      bf16x8 bh = ldfrag(whi + fo);
      bf16x8 bl = ldfrag(wlo + fo);
#pragma unroll
      for (int tile = 0; tile < 2; ++tile) {
        acc[tile][j] = mfma16(al[tile], bh, acc[tile][j]);
        acc[tile][j] = mfma16(ah[tile], bl, acc[tile][j]);
        acc[tile][j] = mfma16(ah[tile], bh, acc[tile][j]);
      }
    }
  }
#pragma unroll
  for (int tile = 0; tile < 2; ++tile) {
#pragma unroll
    for (int j = 0; j < 4; ++j) {
      const int   c  = j * 16 + cc;
      const float bb = b2[c];
#pragma unroll
      for (int i = 0; i < 4; ++i) {
        const int r = tile * 16 + (l >> 4) * 4 + i;
        msg[r * SH + c] = relu(acc[tile][j][i] + bb);
      }
    }
  }

  // ---- per-wave segmented reduction: lane owns column l, walks 32 rows.
  {
    int   cur   = __shfl(d, 0);
    float run   = 0.f;
    bool  first = true;
#pragma unroll 8
    for (int r = 0; r < 32; ++r) {
      float v  = msg[r * SH + l];
      int   dr = __shfl(d, r);          // wave-uniform
      if (r > 0 && dr != cur) {
        float* p = new_states + (size_t)cur * DD + l;
        if (first) atomicAdd(p, run);
        else       *p = run;            // interior run: exclusive owner
        first = false;
        run = 0.f;
        cur = dr;
      }
      run += v;
    }
    atomicAdd(new_states + (size_t)cur * DD + l, run);  // last run
  }
}

// ===========================================================================
// atom_kernel_v2 (proven): readout MFMA + fp32 out + mol sum.
// ===========================================================================
__global__ __launch_bounds__(256, 4)
void atom_kernel_v2(const float* __restrict__ ns,
                    const unsigned short* __restrict__ whi,
                    const unsigned short* __restrict__ wlo,
                    const float* __restrict__ f1b,
                    const float* __restrict__ f2b,
                    const float* __restrict__ wo,
                    const float* __restrict__ bo,
                    float* __restrict__ out)
{
  __shared__ __align__(16) unsigned short Xb[2 * 64 * SH];
  __shared__ __align__(16) unsigned short Hb[2 * 64 * SH];
  unsigned short* Xh = Xb;
  unsigned short* Xl = Xb + 64 * SH;
  unsigned short* Hh = Hb;
  unsigned short* Hl = Hb + 64 * SH;
  float* h2f = (float*)Xb;
  float* oS  = (float*)Hb;

  const int t  = threadIdx.x;
  const int a0 = blockIdx.x * 64;

  {
    const int r  = t >> 2;
    const int k0 = (t & 3) * 16;
    const float4* s4 = (const float4*)(ns + (size_t)(a0 + r) * DD + k0);
#pragma unroll
    for (int f = 0; f < 4; ++f) {
      float4 v = s4[f];
      ushort4 h, lo;
      h.x = bfbits(v.x); lo.x = bfbits(v.x - bfval(h.x));
      h.y = bfbits(v.y); lo.y = bfbits(v.y - bfval(h.y));
      h.z = bfbits(v.z); lo.z = bfbits(v.z - bfval(h.z));
      h.w = bfbits(v.w); lo.w = bfbits(v.w - bfval(h.w));
      *(ushort4*)&Xh[r * SH + k0 + f * 4] = h;
      *(ushort4*)&Xl[r * SH + k0 + f * 4] = lo;
    }
  }

  const int l    = t & 63;
  const int w    = t >> 6;
  const int mrow = w * 16 + (l & 15);
  const int kq   = (l >> 4) * 8;
  const int cc   = l & 15;

  f32x4 acc[4];

#pragma unroll
  for (int j = 0; j < 4; ++j) acc[j] = (f32x4){0.f, 0.f, 0.f, 0.f};
#pragma unroll
  for (int s = 0; s < 2; ++s) {
    bf16x8 ah = ldfrag(&Xh[mrow * SH + s * 32 + kq]);
    bf16x8 al = ldfrag(&Xl[mrow * SH + s * 32 + kq]);
#pragma unroll
    for (int j = 0; j < 4; ++j) {
      const int fo = 4 * 4096 + ((j * 2 + s) * 64 + l) * 8;
      bf16x8 bh = ldfrag(whi + fo);
      bf16x8 bl = ldfrag(wlo + fo);
      acc[j] = mfma16(al, bh, acc[j]);
      acc[j] = mfma16(ah, bl, acc[j]);
      acc[j] = mfma16(ah, bh, acc[j]);
    }
  }
#pragma unroll
  for (int j = 0; j < 4; ++j) {
    const int   c  = j * 16 + cc;
    const float bb = f1b[c];
#pragma unroll
    for (int i = 0; i < 4; ++i) {
      const int r = w * 16 + (l >> 4) * 4 + i;
      float v = relu(acc[j][i] + bb);
      unsigned short hi = bfbits(v);
      Hh[r * SH + c] = hi;
      Hl[r * SH + c] = bfbits(v - bfval(hi));
    }
  }
  __syncthreads();

#pragma unroll
  for (int j = 0; j < 4; ++j) acc[j] = (f32x4){0.f, 0.f, 0.f, 0.f};
#pragma unroll
  for (int s = 0; s < 2; ++s) {
    bf16x8 ah = ldfrag(&Hh[mrow * SH + s * 32 + kq]);
    bf16x8 al = ldfrag(&Hl[mrow * SH + s * 32 + kq]);
#pragma unroll
    for (int j = 0; j < 4; ++j) {
      const int fo = 5 * 4096 + ((j * 2 + s) * 64 + l) * 8;
      bf16x8 bh = ldfrag(whi + fo);
      bf16x8 bl = ldfrag(wlo + fo);
      acc[j] = mfma16(al, bh, acc[j]);
      acc[j] = mfma16(ah, bl, acc[j]);
      acc[j] = mfma16(ah, bh, acc[j]);
    }
  }
#pragma unroll
  for (int j = 0; j < 4; ++j) {
    const int   c  = j * 16 + cc;
    const float bb = f2b[c];
#pragma unroll
    for (int i = 0; i < 4; ++i) {
      const int r = w * 16 + (l >> 4) * 4 + i;
      h2f[r * SH + c] = relu(acc[j][i] + bb);
    }
  }
  __syncthreads();

  {
    const int r  = t >> 2;
    const int c4 = (t & 3) * 4;
    float o4[4] = {0.f, 0.f, 0.f, 0.f};
#pragma unroll 8
    for (int k = 0; k < 64; ++k) {
      const float a = h2f[r * SH + k];
      float4 bw = *(const float4*)&wo[k * OUTD + c4];
      o4[0] += a * bw.x; o4[1] += a * bw.y; o4[2] += a * bw.z; o4[3] += a * bw.w;
    }
#pragma unroll
    for (int j = 0; j < 4; ++j)
      oS[r * 17 + c4 + j] = relu(o4[j] + bo[c4 + j]);
  }
  __syncthreads();

  if (t < 32) {
    const int m = t >> 4;
    const int c = t & 15;
    float s = 0.f;
#pragma unroll
    for (int a = 0; a < 32; ++a) s += oS[(m * 32 + a) * 17 + c];
    out[(blockIdx.x * 2 + m) * OUTD + c] = s;
  }
}

// ===========================================================================
extern "C" void kernel_launch(void* const* d_in, const int* in_sizes, int n_in,
                              void* d_out, int out_size, void* d_ws, size_t ws_size,
                              hipStream_t stream) {
  const float* atom_states = (const float*)d_in[0];
  const int*   edge_src    = (const int*)d_in[1];
  const int*   edge_dst    = (const int*)d_in[2];
  const float* ms0_w = (const float*)d_in[4];
  const float* ms0_b = (const float*)d_in[5];
  const float* ms1_w = (const float*)d_in[6];
  const float* ms1_b = (const float*)d_in[7];
  const float* ms2_w = (const float*)d_in[8];
  const float* ms2_b = (const float*)d_in[9];
  const float* fc1_w = (const float*)d_in[10];
  const float* fc1_b = (const float*)d_in[11];
  const float* fc2_w = (const float*)d_in[12];
  const float* fc2_b = (const float*)d_in[13];
  const float* out_w = (const float*)d_in[14];
  const float* out_b = (const float*)d_in[15];

  char* ws = (char*)d_ws;
  float* new_states = (float*)ws;
  size_t off = (size_t)N_ATOMS * DD * sizeof(float);                   // 32 MiB
  int* eids     = (int*)(ws + off); off += (size_t)N_EDGES * 4;        // +4 MiB
  int* counters = (int*)(ws + off); off += (size_t)N_ATOMS * 4;        // +512 KiB
  int* cursor   = (int*)(ws + off); off += (size_t)N_ATOMS * 4;        // +512 KiB
  int* partial  = (int*)(ws + off); off += 4096;                       // +4 KiB
  unsigned short* whi = (unsigned short*)(ws + off); off += 24576 * 2; // +48 KiB
  unsigned short* wlo = (unsigned short*)(ws + off); off += 24576 * 2; // +48 KiB
  float* Yd = (float*)(ws + off); off += (size_t)N_ATOMS * DD * sizeof(float);
  float* Ys = (float*)(ws + off); off += (size_t)N_ATOMS * DD * sizeof(float);
  int2* ds_sorted = (int2*)(ws + off);
  const size_t need_ds = off + (size_t)N_EDGES * sizeof(int2);         // ~109 MiB
  const int use_ds = (ws_size >= need_ds) ? 1 : 0;   // constant across calls

  hipMemsetAsync(counters, 0, (size_t)N_ATOMS * 4, stream);

  fused_k1<<<6156, 256, 0, stream>>>(edge_dst, ms0_w, ms1_w, ms2_w, fc1_w, fc2_w,
                                     counters, new_states, whi, wlo);
  blocksum_kernel<<<512, 256, 0, stream>>>(counters, partial);
  scanwrite_kernel<<<512, 256, 0, stream>>>(counters, partial, cursor);
  fused_k2<<<6144, 256, 0, stream>>>(atom_states, edge_src, edge_dst, cursor,
                                     ds_sorted, eids, use_ds,
                                     whi, wlo, ms0_b, Yd, Ys);
  edge_kernel_v7<<<N_EDGES / 128, 256, 0, stream>>>(
      Yd, Ys, ds_sorted, eids, edge_src, edge_dst, use_ds,
      whi, wlo, ms1_b, ms2_b, new_states);
  atom_kernel_v2<<<N_ATOMS / 64, 256, 0, stream>>>(
      new_states, whi, wlo, fc1_b, fc2_b, out_w, out_b, (float*)d_out);
}